// Round 8
// baseline (1691.578 us; speedup 1.0000x reference)
//
#include <hip/hip_runtime.h>
#include <hip/hip_fp8.h>
#include <cstdint>
#include <cstddef>

typedef _Float16 f16;
typedef _Float16 f16x8 __attribute__((ext_vector_type(8)));
typedef float f32x4 __attribute__((ext_vector_type(4)));
typedef unsigned char u8;
typedef unsigned long long u64;

#define MFMA16(a,b,c) __builtin_amdgcn_mfma_f32_16x16x32_f16((a),(b),(c),0,0,0)
#define MFMA8(a,b,c)  __builtin_amdgcn_mfma_f32_16x16x32_fp8_fp8((long)(a),(long)(b),(c),0,0,0)

constexpr int Bb = 64, Tt = 48, Ee = 620, Hh = 2400;
constexpr int G3 = 3*Hh;        // 7200
constexpr int EPAD = 640;
constexpr int JT = Hh/16;       // 150
constexpr int KK_HH = Hh/32;    // 75
constexpr int KK_IH = EPAD/32;  // 20
constexpr int NT_ALL = G3/16;   // 450
constexpr int KS = 5;           // K-split for recurrence
constexpr int KKB = KK_HH/KS;   // 15

constexpr size_t WHH_ELEMS = (size_t)NT_ALL*KK_HH*64*8;  // 17,280,000
constexpr size_t WIH_ELEMS = (size_t)NT_ALL*KK_IH*64*8;  // 4,608,000
constexpr size_t X_ELEMS   = (size_t)Bb*Tt*EPAD;
constexpr size_t GI_ELEMS  = (size_t)Bb*Tt*G3;
constexpr size_t HB        = (size_t)Bb*Hh;              // 153,600

constexpr float F16_MIN_NORMAL = 6.103515625e-05f;
constexpr float LO_SCALE = 8388608.0f;   // 2^23
constexpr float LO_INV   = 1.0f/8388608.0f;

__device__ __forceinline__ float sigf(float x){ return 1.0f/(1.0f+expf(-x)); }
__device__ __forceinline__ u8 to_fp8(float x){
    __hip_fp8_e4m3 v(x); return *(u8*)&v;
}

// ---- pack w_hh: hi f16 frags + lo fp8 (residual x 2^23) ----
// elem (nt,kk,l,j): W[nt*16+(l&15)][kk*32+((l>>4)<<3)+j]
__global__ __launch_bounds__(256) void k_pack_whh(const float* __restrict__ w,
                                                  f16* __restrict__ hi,
                                                  u8* __restrict__ lo8){
    size_t idx = (size_t)blockIdx.x*256 + threadIdx.x;
    if (idx >= WHH_ELEMS) return;
    int j = (int)(idx & 7);
    int l = (int)((idx >> 3) & 63);
    size_t rem = idx >> 9;
    int kk = (int)(rem % KK_HH);
    int nt = (int)(rem / KK_HH);
    int row = nt*16 + (l & 15);
    int k   = kk*32 + ((l >> 4) << 3) + j;
    float v = w[(size_t)row*Hh + k];
    f16 h = (fabsf(v) >= F16_MIN_NORMAL) ? (f16)v : (f16)0.0f;
    hi[idx]  = h;
    lo8[idx] = to_fp8((v - (float)h) * LO_SCALE);
}

__global__ __launch_bounds__(256) void k_pack_wih(const float* __restrict__ w, f16* __restrict__ p){
    size_t idx = (size_t)blockIdx.x*256 + threadIdx.x;
    if (idx >= WIH_ELEMS) return;
    int j = (int)(idx & 7);
    int l = (int)((idx >> 3) & 63);
    size_t rem = idx >> 9;
    int kk = (int)(rem % KK_IH);
    int nt = (int)(rem / KK_IH);
    int row = nt*16 + (l & 15);
    int k   = kk*32 + ((l >> 4) << 3) + j;
    float v = (k < Ee) ? w[(size_t)row*Ee + k] : 0.0f;
    p[idx] = (f16)v;
}

__global__ __launch_bounds__(256) void k_gather_x(const int* __restrict__ tokens,
                                                  const float* __restrict__ emb,
                                                  f16* __restrict__ x){
    size_t idx = (size_t)blockIdx.x*256 + threadIdx.x;
    if (idx >= X_ELEMS) return;
    int row = (int)(idx / EPAD);
    int e   = (int)(idx % EPAD);
    int tok = tokens[row];
    float v = (e < Ee) ? emb[(size_t)tok*Ee + e] : 0.0f;
    x[idx] = (f16)v;
}

// ---- gi = x @ w_ih^T: R7 version, verbatim (control) ----
__global__ __launch_bounds__(256) void k_gi_gemm(const f16* __restrict__ x,
                                                 const f16* __restrict__ wp,
                                                 f16* __restrict__ gi){
    __shared__ char smem[61440];   // 3 nt x 20 kk x 1KB
    const int tid = threadIdx.x;
    const int w = tid >> 6;
    const int l = tid & 63;
    const int m0  = blockIdx.x*64 + w*16;
    const int nt0 = blockIdx.y*3;

    {
        const char* base = (const char*)wp;
        for (int off = tid*16; off < 61440; off += 4096){
            int g = off / 20480, rem = off - g*20480;
            const char* src = base + (size_t)(nt0+g)*20480 + rem;
            *(float4*)(smem + off) = *(const float4*)src;
        }
    }
    __syncthreads();

    f32x4 z4 = {0.f,0.f,0.f,0.f};
    f32x4 a0 = z4, a1 = z4, a2 = z4;

    const f16x8* pa = (const f16x8*)(x + (size_t)(m0 + (l & 15))*EPAD + ((l >> 4) << 3));
    const unsigned lbase = (unsigned)l*16u;

    f16x8 ca = pa[0];
    #pragma unroll
    for (int kk=0; kk<KK_IH; ++kk){
        f16x8 na;
        if (kk+1 < KK_IH) na = pa[(size_t)(kk+1)*4];
        f16x8 b0 = *(const f16x8*)(smem +      0u + (unsigned)kk*1024u + lbase);
        f16x8 b1 = *(const f16x8*)(smem + 20480u + (unsigned)kk*1024u + lbase);
        f16x8 b2 = *(const f16x8*)(smem + 40960u + (unsigned)kk*1024u + lbase);
        a0 = MFMA16(ca, b0, a0);
        a1 = MFMA16(ca, b1, a1);
        a2 = MFMA16(ca, b2, a2);
        if (kk+1 < KK_IH) ca = na;
    }
    const int rb = (l >> 4)*4;
    #pragma unroll
    for (int r=0; r<4; ++r){
        int m = m0 + rb + r;
        int b = m / Tt, t = m % Tt;
        size_t base = ((size_t)t*Bb + b)*G3;
        int n0 = nt0*16 + (l & 15);
        gi[base + n0     ] = (f16)a0[r];
        gi[base + n0 + 16] = (f16)a1[r];
        gi[base + n0 + 32] = (f16)a2[r];
    }
}

// ---- recurrence GEMM, K-split, LDS-staged B, waves = 2 m-halves x 2 k-halves ----
__global__ __launch_bounds__(256) void k_gru_mfma(
    const f16* __restrict__ hhi, const f16* __restrict__ hlo, const u8* __restrict__ hq8,
    const f16* __restrict__ whi, const u8* __restrict__ wlo,
    float* __restrict__ part)
{
    __shared__ char smem[69120];   // hi: 3x15x1024=46080 | lo8: 3x15x512=23040
    __shared__ f32x4 red[768];     // [(m2*2+m)*3+g][lane] partial sums from k2=1
    const int tid = threadIdx.x;
    const int w  = tid >> 6;
    const int l  = tid & 63;
    const int m2 = w & 1;          // m-half: rows m2*32 .. m2*32+31
    const int k2 = w >> 1;         // k-half: kk 0..7 | 8..14
    const int jt = blockIdx.x;     // 0..149
    const int ks = blockIdx.y;     // 0..4

    // ---- stage this block's B slice into LDS (once, shared by 4 waves) ----
    {
        const char* bh = (const char*)whi;
        for (int off = tid*16; off < 46080; off += 4096){
            int g = off / 15360, rem = off - g*15360;
            size_t nt = (size_t)(g*JT + jt);
            const char* src = bh + (nt*KK_HH + ks*KKB)*1024 + rem;
            *(float4*)(smem + off) = *(const float4*)src;
        }
        const char* bl = (const char*)wlo;
        for (int off = tid*16; off < 23040; off += 4096){
            int g = off / 7680, rem = off - g*7680;
            size_t nt = (size_t)(g*JT + jt);
            const char* src = bl + (nt*KK_HH + ks*KKB)*512 + rem;
            *(float4*)(smem + 46080 + off) = *(const float4*)src;
        }
    }
    __syncthreads();

    const int kb   = k2 ? 8 : 0;
    const int kcnt = k2 ? 7 : 8;

    const size_t aoff = (size_t)(m2*32 + (l & 15))*Hh + ks*(KKB*32)
                        + (size_t)kb*32 + ((l >> 4) << 3);
    const f16* pah0 = hhi + aoff;  const f16* pah1 = pah0 + (size_t)16*Hh;
    const f16* pal0 = hlo + aoff;  const f16* pal1 = pal0 + (size_t)16*Hh;
    const u8*  paq0 = hq8 + aoff;  const u8*  paq1 = paq0 + (size_t)16*Hh;

    f32x4 z4 = {0.f,0.f,0.f,0.f};
    f32x4 ah00=z4, ah01=z4, ah02=z4, ah10=z4, ah11=z4, ah12=z4;
    f32x4 al00=z4, al01=z4, al02=z4, al10=z4, al11=z4, al12=z4;

    f16x8 cah0 = *(const f16x8*)(pah0);
    f16x8 cal0 = *(const f16x8*)(pal0);
    u64   caq0 = *(const u64*)(paq0);
    f16x8 cah1 = *(const f16x8*)(pah1);
    f16x8 cal1 = *(const f16x8*)(pal1);
    u64   caq1 = *(const u64*)(paq1);

    for (int kk=0; kk<kcnt; ++kk){
        f16x8 nah0, nal0, nah1, nal1; u64 naq0, naq1;
        if (kk+1 < kcnt){
            nah0 = *(const f16x8*)(pah0 + (size_t)(kk+1)*32);
            nal0 = *(const f16x8*)(pal0 + (size_t)(kk+1)*32);
            naq0 = *(const u64*)(paq0 + (size_t)(kk+1)*32);
            nah1 = *(const f16x8*)(pah1 + (size_t)(kk+1)*32);
            nal1 = *(const f16x8*)(pal1 + (size_t)(kk+1)*32);
            naq1 = *(const u64*)(paq1 + (size_t)(kk+1)*32);
        }
        const unsigned kh = (unsigned)(kb+kk)*1024u + (unsigned)l*16u;
        const unsigned kl = (unsigned)(kb+kk)*512u  + (unsigned)l*8u;
        f16x8 b0 = *(const f16x8*)(smem +      0u + kh);
        f16x8 b1 = *(const f16x8*)(smem + 15360u + kh);
        f16x8 b2 = *(const f16x8*)(smem + 30720u + kh);
        u64 w0 = *(const u64*)(smem + 46080u +     0u + kl);
        u64 w1 = *(const u64*)(smem + 46080u +  7680u + kl);
        u64 w2 = *(const u64*)(smem + 46080u + 15360u + kl);

        ah00 = MFMA16(cah0, b0, ah00);
        al00 = MFMA16(cal0, b0, al00);
        al00 = MFMA8(caq0, w0, al00);
        ah01 = MFMA16(cah0, b1, ah01);
        al01 = MFMA16(cal0, b1, al01);
        al01 = MFMA8(caq0, w1, al01);
        ah02 = MFMA16(cah0, b2, ah02);
        al02 = MFMA16(cal0, b2, al02);
        al02 = MFMA8(caq0, w2, al02);

        ah10 = MFMA16(cah1, b0, ah10);
        al10 = MFMA16(cal1, b0, al10);
        al10 = MFMA8(caq1, w0, al10);
        ah11 = MFMA16(cah1, b1, ah11);
        al11 = MFMA16(cal1, b1, al11);
        al11 = MFMA8(caq1, w1, al11);
        ah12 = MFMA16(cah1, b2, ah12);
        al12 = MFMA16(cal1, b2, al12);
        al12 = MFMA8(caq1, w2, al12);

        if (kk+1 < kcnt){
            cah0=nah0; cal0=nal0; caq0=naq0;
            cah1=nah1; cal1=nal1; caq1=naq1;
        }
    }

    // combined hi+lo partial per (m-tile, gate)
    f32x4 v00 = ah00 + al00*LO_INV;
    f32x4 v01 = ah01 + al01*LO_INV;
    f32x4 v02 = ah02 + al02*LO_INV;
    f32x4 v10 = ah10 + al10*LO_INV;
    f32x4 v11 = ah11 + al11*LO_INV;
    f32x4 v12 = ah12 + al12*LO_INV;

    if (k2 == 1){
        red[((m2*2+0)*3+0)*64 + l] = v00;
        red[((m2*2+0)*3+1)*64 + l] = v01;
        red[((m2*2+0)*3+2)*64 + l] = v02;
        red[((m2*2+1)*3+0)*64 + l] = v10;
        red[((m2*2+1)*3+1)*64 + l] = v11;
        red[((m2*2+1)*3+2)*64 + l] = v12;
    }
    __syncthreads();
    if (k2 == 0){
        v00 = v00 + red[((m2*2+0)*3+0)*64 + l];
        v01 = v01 + red[((m2*2+0)*3+1)*64 + l];
        v02 = v02 + red[((m2*2+0)*3+2)*64 + l];
        v10 = v10 + red[((m2*2+1)*3+0)*64 + l];
        v11 = v11 + red[((m2*2+1)*3+1)*64 + l];
        v12 = v12 + red[((m2*2+1)*3+2)*64 + l];

        const int j = jt*16 + (l & 15);
        const int rbase = (l >> 4)*4;
        #pragma unroll
        for (int r=0; r<4; ++r){
            const int b0r = m2*32 + rbase + r;        // m-tile 0 rows
            const int b1r = b0r + 16;                 // m-tile 1 rows
            part[((size_t)(0*KS+ks)*Bb + b0r)*Hh + j] = v00[r];
            part[((size_t)(1*KS+ks)*Bb + b0r)*Hh + j] = v01[r];
            part[((size_t)(2*KS+ks)*Bb + b0r)*Hh + j] = v02[r];
            part[((size_t)(0*KS+ks)*Bb + b1r)*Hh + j] = v10[r];
            part[((size_t)(1*KS+ks)*Bb + b1r)*Hh + j] = v11[r];
            part[((size_t)(2*KS+ks)*Bb + b1r)*Hh + j] = v12[r];
        }
    }
}

// ---- sum K-split partials + gates + h update + length-select output ----
__global__ __launch_bounds__(256) void k_combine(
    int t, const float* __restrict__ part, const f16* __restrict__ gi,
    const float* __restrict__ h32, float* __restrict__ nh32,
    f16* __restrict__ nhhi, f16* __restrict__ nhlo, u8* __restrict__ nhq8,
    const float* __restrict__ bhh, const int* __restrict__ lens,
    float* __restrict__ out)
{
    const int idx = blockIdx.x*256 + threadIdx.x;   // 0 .. 153599
    const int b = idx / Hh, j = idx - b*Hh;
    float sr = 0.f, sz = 0.f, sn = 0.f;
    #pragma unroll
    for (int ks=0; ks<KS; ++ks){
        sr += part[((size_t)(0*KS+ks)*Bb + b)*Hh + j];
        sz += part[((size_t)(1*KS+ks)*Bb + b)*Hh + j];
        sn += part[((size_t)(2*KS+ks)*Bb + b)*Hh + j];
    }
    const f16* git = gi + ((size_t)t*Bb + b)*G3;
    float rg = sigf((float)git[j]        + sr + bhh[j]);
    float zg = sigf((float)git[Hh + j]   + sz + bhh[Hh + j]);
    float ng = tanhf((float)git[2*Hh + j] + rg*(sn + bhh[2*Hh + j]));
    float hp = h32[idx];
    float hn = (1.0f - zg)*ng + zg*hp;
    nh32[idx] = hn;
    f16 h16 = (fabsf(hn) >= F16_MIN_NORMAL) ? (f16)hn : (f16)0.0f;
    nhhi[idx] = h16;
    nhlo[idx] = (f16)((hn - (float)h16)*LO_SCALE);
    nhq8[idx] = to_fp8(hn);
    if (lens[b] - 1 == t) out[idx] = hn;
}

// ---- fallback (small ws): plain fp32 ----
__global__ __launch_bounds__(256) void k_fb_step(
    int t, const float* __restrict__ hcur, float* __restrict__ hnext,
    const int* __restrict__ tokens, const int* __restrict__ lens,
    const float* __restrict__ emb, const float* __restrict__ wih,
    const float* __restrict__ whh, const float* __restrict__ bhh,
    float* __restrict__ out)
{
    __shared__ float sbuf[64][17];
    __shared__ int stok[64];
    const int tid = threadIdx.x;
    const int jl = tid & 7, rl = tid >> 3;
    const int j = blockIdx.x*8 + jl;
    if (tid < 64) stok[tid] = tokens[tid*Tt + t];

    float accr[2]={0.f,0.f}, accz[2]={0.f,0.f}, accnh[2]={0.f,0.f}, accni[2]={0.f,0.f};

    for (int k0=0; k0<Hh; k0+=16){
        __syncthreads();
        for (int e=tid; e<1024; e+=256)
            sbuf[e>>4][e&15] = hcur[(size_t)(e>>4)*Hh + k0 + (e&15)];
        __syncthreads();
        for (int kk=0; kk<16; ++kk){
            int k = k0 + kk;
            float wr = whh[(size_t)j*Hh + k];
            float wz = whh[(size_t)(Hh + j)*Hh + k];
            float wn = whh[(size_t)(2*Hh + j)*Hh + k];
            #pragma unroll
            for (int rr=0; rr<2; ++rr){
                float hv = sbuf[rl*2 + rr][kk];
                accr[rr] += wr*hv; accz[rr] += wz*hv; accnh[rr] += wn*hv;
            }
        }
    }
    for (int k0=0; k0<Ee; k0+=16){
        int lim = (Ee - k0 < 16) ? (Ee - k0) : 16;
        __syncthreads();
        for (int e=tid; e<1024; e+=256){
            int rr = e>>4, kkk = e&15;
            sbuf[rr][kkk] = (kkk < lim) ? emb[(size_t)stok[rr]*Ee + k0 + kkk] : 0.0f;
        }
        __syncthreads();
        for (int kk=0; kk<lim; ++kk){
            int k = k0 + kk;
            float wr = wih[(size_t)j*Ee + k];
            float wz = wih[(size_t)(Hh + j)*Ee + k];
            float wn = wih[(size_t)(2*Hh + j)*Ee + k];
            #pragma unroll
            for (int rr=0; rr<2; ++rr){
                float hv = sbuf[rl*2 + rr][kk];
                accr[rr] += wr*hv; accz[rr] += wz*hv; accni[rr] += wn*hv;
            }
        }
    }
    const float br = bhh[j], bz = bhh[Hh + j], bn = bhh[2*Hh + j];
    #pragma unroll
    for (int rr=0; rr<2; ++rr){
        int b = rl*2 + rr;
        float rg = sigf(accr[rr] + br);
        float zg = sigf(accz[rr] + bz);
        float ng = tanhf(accni[rr] + rg*(accnh[rr] + bn));
        float hp = hcur[(size_t)b*Hh + j];
        float hn = (1.0f - zg)*ng + zg*hp;
        hnext[(size_t)b*Hh + j] = hn;
        if (lens[b] - 1 == t) out[(size_t)b*Hh + j] = hn;
    }
}

static inline size_t alignup(size_t v){ return (v + 255) & ~(size_t)255; }

extern "C" void kernel_launch(void* const* d_in, const int* in_sizes, int n_in,
                              void* d_out, int out_size, void* d_ws, size_t ws_size,
                              hipStream_t stream)
{
    const int*   tokens = (const int*)d_in[0];
    const int*   lens   = (const int*)d_in[1];
    const float* emb    = (const float*)d_in[2];
    const float* wih    = (const float*)d_in[3];
    const float* whh    = (const float*)d_in[4];
    const float* bhh    = (const float*)d_in[5];
    float* out = (float*)d_out;

    char* ws = (char*)d_ws;
    size_t o = 0;
    const size_t o_whi  = o; o = alignup(o + WHH_ELEMS*2);
    const size_t o_wlo8 = o; o = alignup(o + WHH_ELEMS);
    const size_t o_wih  = o; o = alignup(o + WIH_ELEMS*2);  // reused as `part` after gi
    const size_t o_x    = o; o = alignup(o + X_ELEMS*2);
    const size_t o_gi   = o; o = alignup(o + GI_ELEMS*2);
    const size_t hbytes = HB*2 + HB*2 + HB + HB*4;   // hi, lo, q8, h32
    const size_t o_hbuf = o; o = alignup(o + 2*hbytes);
    const size_t need = o;   // ~112 MB

    if (ws_size >= need) {
        f16* whip = (f16*)(ws + o_whi);
        u8*  wlop = (u8*)(ws + o_wlo8);
        f16* wihp = (f16*)(ws + o_wih);
        float* part = (float*)(ws + o_wih);   // overlays wihp (dead after gi GEMM)
        f16* xp   = (f16*)(ws + o_x);
        f16* gip  = (f16*)(ws + o_gi);
        char* hb = ws + o_hbuf;
        f16* hhi[2]; f16* hlo[2]; u8* hq8[2]; float* h32[2];
        for (int i=0; i<2; ++i){
            char* p = hb + i*hbytes;
            hhi[i] = (f16*)p;
            hlo[i] = (f16*)(p + HB*2);
            hq8[i] = (u8*)(p + HB*4);
            h32[i] = (float*)(p + HB*5);
        }

        hipMemsetAsync(hb, 0, 2*hbytes, stream);
        k_pack_whh<<<dim3((unsigned)((WHH_ELEMS+255)/256)), dim3(256), 0, stream>>>(whh, whip, wlop);
        k_pack_wih<<<dim3((unsigned)((WIH_ELEMS+255)/256)), dim3(256), 0, stream>>>(wih, wihp);
        k_gather_x<<<dim3((unsigned)((X_ELEMS+255)/256)),  dim3(256), 0, stream>>>(tokens, emb, xp);
        k_gi_gemm<<<dim3(48,150), dim3(256), 0, stream>>>(xp, wihp, gip);
        for (int t=0; t<Tt; ++t){
            int c = t & 1, n = c ^ 1;
            k_gru_mfma<<<dim3(JT, KS), dim3(256), 0, stream>>>(
                hhi[c], hlo[c], hq8[c], whip, wlop, part);
            k_combine<<<dim3(600), dim3(256), 0, stream>>>(t, part, gip,
                h32[c], h32[n], hhi[n], hlo[n], hq8[n], bhh, lens, out);
        }
    } else {
        float* h32 = (float*)ws;
        float* hbuf[2] = { h32, h32 + HB };
        hipMemsetAsync(ws, 0, 2*HB*4, stream);
        for (int t=0; t<Tt; ++t){
            int c = t & 1, n = c ^ 1;
            k_fb_step<<<dim3(300), dim3(256), 0, stream>>>(t, hbuf[c], hbuf[n],
                tokens, lens, emb, wih, whh, bhh, out);
        }
    }
}

// Round 9
// 1396.751 us; speedup vs baseline: 1.2111x; 1.2111x over previous
//
#include <hip/hip_runtime.h>
#include <hip/hip_fp8.h>
#include <cstdint>
#include <cstddef>

typedef _Float16 f16;
typedef _Float16 f16x8 __attribute__((ext_vector_type(8)));
typedef float f32x4 __attribute__((ext_vector_type(4)));
typedef unsigned char u8;
typedef unsigned long long u64;

#define MFMA16(a,b,c) __builtin_amdgcn_mfma_f32_16x16x32_f16((a),(b),(c),0,0,0)
#define MFMA8(a,b,c)  __builtin_amdgcn_mfma_f32_16x16x32_fp8_fp8((long)(a),(long)(b),(c),0,0,0)

constexpr int Bb = 64, Tt = 48, Ee = 620, Hh = 2400;
constexpr int G3 = 3*Hh;        // 7200
constexpr int EPAD = 640;
constexpr int JT = Hh/16;       // 150
constexpr int KK_HH = Hh/32;    // 75
constexpr int KK_IH = EPAD/32;  // 20
constexpr int NT_ALL = G3/16;   // 450
constexpr int KS = 5;           // K-split for recurrence
constexpr int KKB = KK_HH/KS;   // 15

constexpr size_t WHH_ELEMS = (size_t)NT_ALL*KK_HH*64*8;  // 17,280,000
constexpr size_t WIH_ELEMS = (size_t)NT_ALL*KK_IH*64*8;  // 4,608,000
constexpr size_t X_ELEMS   = (size_t)Bb*Tt*EPAD;
constexpr size_t GI_ELEMS  = (size_t)Bb*Tt*G3;
constexpr size_t HB        = (size_t)Bb*Hh;              // 153,600

constexpr float F16_MIN_NORMAL = 6.103515625e-05f;
constexpr float LO_SCALE = 8388608.0f;   // 2^23
constexpr float LO_INV   = 1.0f/8388608.0f;

__device__ __forceinline__ float sigf(float x){ return 1.0f/(1.0f+expf(-x)); }
__device__ __forceinline__ u8 to_fp8(float x){
    __hip_fp8_e4m3 v(x); return *(u8*)&v;
}

// ---- pack w_hh: hi f16 frags + lo fp8 (residual x 2^23) ----
// elem (nt,kk,l,j): W[nt*16+(l&15)][kk*32+((l>>4)<<3)+j]
__global__ __launch_bounds__(256) void k_pack_whh(const float* __restrict__ w,
                                                  f16* __restrict__ hi,
                                                  u8* __restrict__ lo8){
    size_t idx = (size_t)blockIdx.x*256 + threadIdx.x;
    if (idx >= WHH_ELEMS) return;
    int j = (int)(idx & 7);
    int l = (int)((idx >> 3) & 63);
    size_t rem = idx >> 9;
    int kk = (int)(rem % KK_HH);
    int nt = (int)(rem / KK_HH);
    int row = nt*16 + (l & 15);
    int k   = kk*32 + ((l >> 4) << 3) + j;
    float v = w[(size_t)row*Hh + k];
    f16 h = (fabsf(v) >= F16_MIN_NORMAL) ? (f16)v : (f16)0.0f;
    hi[idx]  = h;
    lo8[idx] = to_fp8((v - (float)h) * LO_SCALE);
}

__global__ __launch_bounds__(256) void k_pack_wih(const float* __restrict__ w, f16* __restrict__ p){
    size_t idx = (size_t)blockIdx.x*256 + threadIdx.x;
    if (idx >= WIH_ELEMS) return;
    int j = (int)(idx & 7);
    int l = (int)((idx >> 3) & 63);
    size_t rem = idx >> 9;
    int kk = (int)(rem % KK_IH);
    int nt = (int)(rem / KK_IH);
    int row = nt*16 + (l & 15);
    int k   = kk*32 + ((l >> 4) << 3) + j;
    float v = (k < Ee) ? w[(size_t)row*Ee + k] : 0.0f;
    p[idx] = (f16)v;
}

__global__ __launch_bounds__(256) void k_gather_x(const int* __restrict__ tokens,
                                                  const float* __restrict__ emb,
                                                  f16* __restrict__ x){
    size_t idx = (size_t)blockIdx.x*256 + threadIdx.x;
    if (idx >= X_ELEMS) return;
    int row = (int)(idx / EPAD);
    int e   = (int)(idx % EPAD);
    int tok = tokens[row];
    float v = (e < Ee) ? emb[(size_t)tok*Ee + e] : 0.0f;
    x[idx] = (f16)v;
}

// ---- gi = x @ w_ih^T: 512 thr, 8 m-tile waves share one LDS B-stage ----
__global__ __launch_bounds__(512) void k_gi_gemm(const f16* __restrict__ x,
                                                 const f16* __restrict__ wp,
                                                 f16* __restrict__ gi){
    __shared__ char smem[61440];   // 3 nt x 20 kk x 1KB
    const int tid = threadIdx.x;
    const int wv = tid >> 6;       // 0..7 m-tile waves
    const int l  = tid & 63;
    const int m0  = blockIdx.x*128 + wv*16;
    const int nt0 = blockIdx.y*3;

    {
        const char* base = (const char*)wp;
        for (int off = tid*16; off < 61440; off += 8192){
            int g = off / 20480, rem = off - g*20480;
            const char* src = base + (size_t)(nt0+g)*20480 + rem;
            *(float4*)(smem + off) = *(const float4*)src;
        }
    }
    __syncthreads();

    f32x4 z4 = {0.f,0.f,0.f,0.f};
    f32x4 a0 = z4, a1 = z4, a2 = z4;

    const f16x8* pa = (const f16x8*)(x + (size_t)(m0 + (l & 15))*EPAD + ((l >> 4) << 3));
    const unsigned lbase = (unsigned)l*16u;

    f16x8 ca = pa[0];
    #pragma unroll
    for (int kk=0; kk<KK_IH; ++kk){
        f16x8 na;
        if (kk+1 < KK_IH) na = pa[(size_t)(kk+1)*4];
        f16x8 b0 = *(const f16x8*)(smem +      0u + (unsigned)kk*1024u + lbase);
        f16x8 b1 = *(const f16x8*)(smem + 20480u + (unsigned)kk*1024u + lbase);
        f16x8 b2 = *(const f16x8*)(smem + 40960u + (unsigned)kk*1024u + lbase);
        a0 = MFMA16(ca, b0, a0);
        a1 = MFMA16(ca, b1, a1);
        a2 = MFMA16(ca, b2, a2);
        if (kk+1 < KK_IH) ca = na;
    }
    const int rb = (l >> 4)*4;
    #pragma unroll
    for (int r=0; r<4; ++r){
        int m = m0 + rb + r;
        int b = m / Tt, t = m % Tt;
        size_t base = ((size_t)t*Bb + b)*G3;
        int n0 = nt0*16 + (l & 15);
        gi[base + n0     ] = (f16)a0[r];
        gi[base + n0 + 16] = (f16)a1[r];
        gi[base + n0 + 32] = (f16)a2[r];
    }
}

// ---- recurrence GEMM: 512 thr = 4 m-waves x 2 k-halves; B-hi LDS, B-lo8 global ----
__global__ __launch_bounds__(512) void k_gru_mfma(
    const f16* __restrict__ hhi, const f16* __restrict__ hlo, const u8* __restrict__ hq8,
    const f16* __restrict__ whi, const u8* __restrict__ wlo,
    float* __restrict__ part)
{
    __shared__ char smem[46080];   // B-hi: 3 nt x 15 kk x 1KB
    __shared__ f32x4 red[768];     // [m][g][lane] partials from kh=1
    const int tid = threadIdx.x;
    const int wv = tid >> 6;       // 0..7
    const int l  = tid & 63;
    const int m  = wv & 3;         // m-tile (16 batch rows)
    const int kh = wv >> 2;        // k-half of the 15 kk
    const int jt = blockIdx.x;     // 0..149
    const int ks = blockIdx.y;     // 0..4

    // stage B-hi once (shared by 8 waves)
    {
        const char* bh = (const char*)whi;
        for (int off = tid*16; off < 46080; off += 8192){
            int g = off / 15360, rem = off - g*15360;
            size_t nt = (size_t)(g*JT + jt);
            const char* src = bh + (nt*KK_HH + ks*KKB)*1024 + rem;
            *(float4*)(smem + off) = *(const float4*)src;
        }
    }
    __syncthreads();

    const int kb   = kh ? 8 : 0;
    const int kcnt = kh ? 7 : 8;

    const size_t aoff = (size_t)(m*16 + (l & 15))*Hh + ks*(KKB*32)
                        + (size_t)kb*32 + ((l >> 4) << 3);
    const f16* pah = hhi + aoff;
    const f16* pal = hlo + aoff;
    const u8*  paq = hq8 + aoff;

    const u8* pbl0 = wlo + ((size_t)((0*JT+jt)*KK_HH + ks*KKB + kb))*512 + (size_t)l*8;
    const u8* pbl1 = wlo + ((size_t)((1*JT+jt)*KK_HH + ks*KKB + kb))*512 + (size_t)l*8;
    const u8* pbl2 = wlo + ((size_t)((2*JT+jt)*KK_HH + ks*KKB + kb))*512 + (size_t)l*8;

    f32x4 z4 = {0.f,0.f,0.f,0.f};
    f32x4 ah0=z4, ah1=z4, ah2=z4;
    f32x4 al0=z4, al1=z4, al2=z4;

    f16x8 cah = *(const f16x8*)(pah);
    f16x8 cal = *(const f16x8*)(pal);
    u64   caq = *(const u64*)(paq);
    u64   cl0 = *(const u64*)(pbl0);
    u64   cl1 = *(const u64*)(pbl1);
    u64   cl2 = *(const u64*)(pbl2);

    for (int kk=0; kk<kcnt; ++kk){
        f16x8 nah, nal; u64 naq, nl0, nl1, nl2;
        if (kk+1 < kcnt){
            nah = *(const f16x8*)(pah + (size_t)(kk+1)*32);
            nal = *(const f16x8*)(pal + (size_t)(kk+1)*32);
            naq = *(const u64*)(paq + (size_t)(kk+1)*32);
            nl0 = *(const u64*)(pbl0 + (size_t)(kk+1)*512);
            nl1 = *(const u64*)(pbl1 + (size_t)(kk+1)*512);
            nl2 = *(const u64*)(pbl2 + (size_t)(kk+1)*512);
        }
        const unsigned khh = (unsigned)(kb+kk)*1024u + (unsigned)l*16u;
        f16x8 b0 = *(const f16x8*)(smem +      0u + khh);
        f16x8 b1 = *(const f16x8*)(smem + 15360u + khh);
        f16x8 b2 = *(const f16x8*)(smem + 30720u + khh);

        ah0 = MFMA16(cah, b0, ah0);
        al0 = MFMA16(cal, b0, al0);
        al0 = MFMA8(caq, cl0, al0);
        ah1 = MFMA16(cah, b1, ah1);
        al1 = MFMA16(cal, b1, al1);
        al1 = MFMA8(caq, cl1, al1);
        ah2 = MFMA16(cah, b2, ah2);
        al2 = MFMA16(cal, b2, al2);
        al2 = MFMA8(caq, cl2, al2);

        if (kk+1 < kcnt){
            cah=nah; cal=nal; caq=naq;
            cl0=nl0; cl1=nl1; cl2=nl2;
        }
    }

    f32x4 v0 = ah0 + al0*LO_INV;
    f32x4 v1 = ah1 + al1*LO_INV;
    f32x4 v2 = ah2 + al2*LO_INV;

    if (kh == 1){
        red[(m*3+0)*64 + l] = v0;
        red[(m*3+1)*64 + l] = v1;
        red[(m*3+2)*64 + l] = v2;
    }
    __syncthreads();
    if (kh == 0){
        v0 = v0 + red[(m*3+0)*64 + l];
        v1 = v1 + red[(m*3+1)*64 + l];
        v2 = v2 + red[(m*3+2)*64 + l];

        const int j = jt*16 + (l & 15);
        const int rbase = (l >> 4)*4;
        #pragma unroll
        for (int r=0; r<4; ++r){
            const int b = m*16 + rbase + r;
            part[((size_t)(0*KS+ks)*Bb + b)*Hh + j] = v0[r];
            part[((size_t)(1*KS+ks)*Bb + b)*Hh + j] = v1[r];
            part[((size_t)(2*KS+ks)*Bb + b)*Hh + j] = v2[r];
        }
    }
}

// ---- sum K-split partials + gates + h update + length-select output ----
__global__ __launch_bounds__(256) void k_combine(
    int t, const float* __restrict__ part, const f16* __restrict__ gi,
    const float* __restrict__ h32, float* __restrict__ nh32,
    f16* __restrict__ nhhi, f16* __restrict__ nhlo, u8* __restrict__ nhq8,
    const float* __restrict__ bhh, const int* __restrict__ lens,
    float* __restrict__ out)
{
    const int idx = blockIdx.x*256 + threadIdx.x;   // 0 .. 153599
    const int b = idx / Hh, j = idx - b*Hh;
    float sr = 0.f, sz = 0.f, sn = 0.f;
    #pragma unroll
    for (int ks=0; ks<KS; ++ks){
        sr += part[((size_t)(0*KS+ks)*Bb + b)*Hh + j];
        sz += part[((size_t)(1*KS+ks)*Bb + b)*Hh + j];
        sn += part[((size_t)(2*KS+ks)*Bb + b)*Hh + j];
    }
    const f16* git = gi + ((size_t)t*Bb + b)*G3;
    float rg = sigf((float)git[j]        + sr + bhh[j]);
    float zg = sigf((float)git[Hh + j]   + sz + bhh[Hh + j]);
    float ng = tanhf((float)git[2*Hh + j] + rg*(sn + bhh[2*Hh + j]));
    float hp = h32[idx];
    float hn = (1.0f - zg)*ng + zg*hp;
    nh32[idx] = hn;
    f16 h16 = (fabsf(hn) >= F16_MIN_NORMAL) ? (f16)hn : (f16)0.0f;
    nhhi[idx] = h16;
    nhlo[idx] = (f16)((hn - (float)h16)*LO_SCALE);
    nhq8[idx] = to_fp8(hn);
    if (lens[b] - 1 == t) out[idx] = hn;
}

// ---- fallback (small ws): plain fp32 ----
__global__ __launch_bounds__(256) void k_fb_step(
    int t, const float* __restrict__ hcur, float* __restrict__ hnext,
    const int* __restrict__ tokens, const int* __restrict__ lens,
    const float* __restrict__ emb, const float* __restrict__ wih,
    const float* __restrict__ whh, const float* __restrict__ bhh,
    float* __restrict__ out)
{
    __shared__ float sbuf[64][17];
    __shared__ int stok[64];
    const int tid = threadIdx.x;
    const int jl = tid & 7, rl = tid >> 3;
    const int j = blockIdx.x*8 + jl;
    if (tid < 64) stok[tid] = tokens[tid*Tt + t];

    float accr[2]={0.f,0.f}, accz[2]={0.f,0.f}, accnh[2]={0.f,0.f}, accni[2]={0.f,0.f};

    for (int k0=0; k0<Hh; k0+=16){
        __syncthreads();
        for (int e=tid; e<1024; e+=256)
            sbuf[e>>4][e&15] = hcur[(size_t)(e>>4)*Hh + k0 + (e&15)];
        __syncthreads();
        for (int kk=0; kk<16; ++kk){
            int k = k0 + kk;
            float wr = whh[(size_t)j*Hh + k];
            float wz = whh[(size_t)(Hh + j)*Hh + k];
            float wn = whh[(size_t)(2*Hh + j)*Hh + k];
            #pragma unroll
            for (int rr=0; rr<2; ++rr){
                float hv = sbuf[rl*2 + rr][kk];
                accr[rr] += wr*hv; accz[rr] += wz*hv; accnh[rr] += wn*hv;
            }
        }
    }
    for (int k0=0; k0<Ee; k0+=16){
        int lim = (Ee - k0 < 16) ? (Ee - k0) : 16;
        __syncthreads();
        for (int e=tid; e<1024; e+=256){
            int rr = e>>4, kkk = e&15;
            sbuf[rr][kkk] = (kkk < lim) ? emb[(size_t)stok[rr]*Ee + k0 + kkk] : 0.0f;
        }
        __syncthreads();
        for (int kk=0; kk<lim; ++kk){
            int k = k0 + kk;
            float wr = wih[(size_t)j*Ee + k];
            float wz = wih[(size_t)(Hh + j)*Ee + k];
            float wn = wih[(size_t)(2*Hh + j)*Ee + k];
            #pragma unroll
            for (int rr=0; rr<2; ++rr){
                float hv = sbuf[rl*2 + rr][kk];
                accr[rr] += wr*hv; accz[rr] += wz*hv; accni[rr] += wn*hv;
            }
        }
    }
    const float br = bhh[j], bz = bhh[Hh + j], bn = bhh[2*Hh + j];
    #pragma unroll
    for (int rr=0; rr<2; ++rr){
        int b = rl*2 + rr;
        float rg = sigf(accr[rr] + br);
        float zg = sigf(accz[rr] + bz);
        float ng = tanhf(accni[rr] + rg*(accnh[rr] + bn));
        float hp = hcur[(size_t)b*Hh + j];
        float hn = (1.0f - zg)*ng + zg*hp;
        hnext[(size_t)b*Hh + j] = hn;
        if (lens[b] - 1 == t) out[(size_t)b*Hh + j] = hn;
    }
}

static inline size_t alignup(size_t v){ return (v + 255) & ~(size_t)255; }

extern "C" void kernel_launch(void* const* d_in, const int* in_sizes, int n_in,
                              void* d_out, int out_size, void* d_ws, size_t ws_size,
                              hipStream_t stream)
{
    const int*   tokens = (const int*)d_in[0];
    const int*   lens   = (const int*)d_in[1];
    const float* emb    = (const float*)d_in[2];
    const float* wih    = (const float*)d_in[3];
    const float* whh    = (const float*)d_in[4];
    const float* bhh    = (const float*)d_in[5];
    float* out = (float*)d_out;

    char* ws = (char*)d_ws;
    size_t o = 0;
    const size_t o_whi  = o; o = alignup(o + WHH_ELEMS*2);
    const size_t o_wlo8 = o; o = alignup(o + WHH_ELEMS);
    const size_t o_wih  = o; o = alignup(o + WIH_ELEMS*2);  // reused as `part` after gi
    const size_t o_x    = o; o = alignup(o + X_ELEMS*2);
    const size_t o_gi   = o; o = alignup(o + GI_ELEMS*2);
    const size_t hbytes = HB*2 + HB*2 + HB + HB*4;   // hi, lo, q8, h32
    const size_t o_hbuf = o; o = alignup(o + 2*hbytes);
    const size_t need = o;   // ~112 MB

    if (ws_size >= need) {
        f16* whip = (f16*)(ws + o_whi);
        u8*  wlop = (u8*)(ws + o_wlo8);
        f16* wihp = (f16*)(ws + o_wih);
        float* part = (float*)(ws + o_wih);   // overlays wihp (dead after gi GEMM)
        f16* xp   = (f16*)(ws + o_x);
        f16* gip  = (f16*)(ws + o_gi);
        char* hb = ws + o_hbuf;
        f16* hhi[2]; f16* hlo[2]; u8* hq8[2]; float* h32[2];
        for (int i=0; i<2; ++i){
            char* p = hb + i*hbytes;
            hhi[i] = (f16*)p;
            hlo[i] = (f16*)(p + HB*2);
            hq8[i] = (u8*)(p + HB*4);
            h32[i] = (float*)(p + HB*5);
        }

        hipMemsetAsync(hb, 0, 2*hbytes, stream);
        k_pack_whh<<<dim3((unsigned)((WHH_ELEMS+255)/256)), dim3(256), 0, stream>>>(whh, whip, wlop);
        k_pack_wih<<<dim3((unsigned)((WIH_ELEMS+255)/256)), dim3(256), 0, stream>>>(wih, wihp);
        k_gather_x<<<dim3((unsigned)((X_ELEMS+255)/256)),  dim3(256), 0, stream>>>(tokens, emb, xp);
        k_gi_gemm<<<dim3(24,150), dim3(512), 0, stream>>>(xp, wihp, gip);
        for (int t=0; t<Tt; ++t){
            int c = t & 1, n = c ^ 1;
            k_gru_mfma<<<dim3(JT, KS), dim3(512), 0, stream>>>(
                hhi[c], hlo[c], hq8[c], whip, wlop, part);
            k_combine<<<dim3(600), dim3(256), 0, stream>>>(t, part, gip,
                h32[c], h32[n], hhi[n], hlo[n], hq8[n], bhh, lens, out);
        }
    } else {
        float* h32 = (float*)ws;
        float* hbuf[2] = { h32, h32 + HB };
        hipMemsetAsync(ws, 0, 2*HB*4, stream);
        for (int t=0; t<Tt; ++t){
            int c = t & 1, n = c ^ 1;
            k_fb_step<<<dim3(300), dim3(256), 0, stream>>>(t, hbuf[c], hbuf[n],
                tokens, lens, emb, wih, whh, bhh, out);
        }
    }
}